// Round 2
// baseline (101.024 us; speedup 1.0000x reference)
//
#include <hip/hip_runtime.h>

#define NTHR 256
#define NROW 5000
#define NB1 2503
#define NB2 1255
#define NB3 631
#define NB4 319

// db4 filters (exact values from reference)
__device__ __constant__ float DEC_LO[8] = {
    -0.010597401784997278f, 0.032883011666982945f, 0.030841381835986965f,
    -0.18703481171888114f, -0.02798376941698385f, 0.6308807679295904f,
    0.7148465705525415f, 0.23037781330885523f};
__device__ __constant__ float DEC_HI[8] = {
    -0.23037781330885523f, 0.7148465705525415f, -0.6308807679295904f,
    -0.02798376941698385f, 0.18703481171888114f, 0.030841381835986965f,
    -0.032883011666982945f, -0.010597401784997278f};
__device__ __constant__ float REC_LO[8] = {
    0.23037781330885523f, 0.7148465705525415f, 0.6308807679295904f,
    -0.02798376941698385f, -0.18703481171888114f, 0.030841381835986965f,
    0.032883011666982945f, -0.010597401784997278f};
__device__ __constant__ float REC_HI[8] = {
    -0.010597401784997278f, -0.032883011666982945f, 0.030841381835986965f,
    0.18703481171888114f, -0.02798376941698385f, -0.6308807679295904f,
    0.7148465705525415f, -0.23037781330885523f};

// y[i] = sum_t DEC[t] * xe[2i+7-t]; xe = sym-pad(7,7)[1:]
__device__ __forceinline__ void dwt_step(const float* __restrict__ src, int n, int n_out,
                                         float* __restrict__ oa, float* __restrict__ od,
                                         int tid) {
  for (int i = tid; i < n_out; i += NTHR) {
    float sa = 0.f, sd = 0.f;
    const int base = 2 * i;
#pragma unroll
    for (int j = 0; j < 8; ++j) {
      const int p = base + j;  // tap index t = 7-j
      const int q = (p < 6) ? (5 - p) : ((p < n + 6) ? (p - 6) : (2 * n + 5 - p));
      const float v = src[q];
      sa = fmaf(DEC_LO[7 - j], v, sa);
      sd = fmaf(DEC_HI[7 - j], v, sd);
    }
    oa[i] = sa;
    od[i] = sd;
  }
}

// out[2i], out[2i+1] from ca[i..i+3], cd[i..i+3]; i in [0, n-4]; out len 2n-6
template <bool CA, bool CD>
__device__ __forceinline__ void idwt_lds(const float* __restrict__ ca,
                                         const float* __restrict__ cd, int n,
                                         float* __restrict__ out, int tid) {
  for (int i = tid; i <= n - 4; i += NTHR) {
    float e = 0.f, o = 0.f;
#pragma unroll
    for (int s = 0; s < 4; ++s) {
      const int j = i + 3 - s;
      if (CA) {
        const float a = ca[j];
        e = fmaf(REC_LO[2 * s], a, e);
        o = fmaf(REC_LO[2 * s + 1], a, o);
      }
      if (CD) {
        const float d = cd[j];
        e = fmaf(REC_HI[2 * s], d, e);
        o = fmaf(REC_HI[2 * s + 1], d, o);
      }
    }
    out[2 * i] = e;
    out[2 * i + 1] = o;
  }
}

template <bool CA, bool CD>
__device__ __forceinline__ void idwt_glob(const float* __restrict__ ca,
                                          const float* __restrict__ cd, int n,
                                          float* __restrict__ out, int tid) {
  float2* out2 = reinterpret_cast<float2*>(out);
  for (int i = tid; i <= n - 4; i += NTHR) {
    float e = 0.f, o = 0.f;
#pragma unroll
    for (int s = 0; s < 4; ++s) {
      const int j = i + 3 - s;
      if (CA) {
        const float a = ca[j];
        e = fmaf(REC_LO[2 * s], a, e);
        o = fmaf(REC_LO[2 * s + 1], a, o);
      }
      if (CD) {
        const float d = cd[j];
        e = fmaf(REC_HI[2 * s], d, e);
        o = fmaf(REC_HI[2 * s + 1], d, o);
      }
    }
    out2[i] = make_float2(e, o);
  }
}

__global__ __launch_bounds__(NTHR) void wavelet_kernel(const float* __restrict__ x,
                                                       float* __restrict__ out_physio,
                                                       float* __restrict__ out_identity) {
  __shared__ __align__(16) float sx[5008];   // x; later s1 = idwt(0, d2)
  __shared__ float sa1[2504];                // a1; later r1
  __shared__ float sd1[2504];
  __shared__ float sa2[1256];                // a2; later r2
  __shared__ float sd2[1256];
  __shared__ float sa3[632];                 // a3; later r3
  __shared__ float sd3[632];
  __shared__ float sa4[320];
  __shared__ float sd4[320];

  const int b = blockIdx.x;
  const int tid = threadIdx.x;
  const float* xrow = x + (size_t)b * NROW;

  // load row (5000 f32 = 1250 float4, 16B-aligned since 20000 % 16 == 0)
  {
    const float4* x4 = reinterpret_cast<const float4*>(xrow);
    float4* sx4 = reinterpret_cast<float4*>(sx);
    for (int i = tid; i < NROW / 4; i += NTHR) sx4[i] = x4[i];
  }
  __syncthreads();

  // decomposition
  dwt_step(sx, NROW, NB1, sa1, sd1, tid);
  __syncthreads();
  dwt_step(sa1, NB1, NB2, sa2, sd2, tid);
  __syncthreads();
  dwt_step(sa2, NB2, NB3, sa3, sd3, tid);
  __syncthreads();
  dwt_step(sa3, NB3, NB4, sa4, sd4, tid);
  __syncthreads();

  // physio = waverec([a4, d4, d3, 0, 0])
  idwt_lds<true, true>(sa4, sd4, NB4, sa3, tid);   // r3: len 632 -> read as 631
  __syncthreads();
  idwt_lds<true, true>(sa3, sd3, NB3, sa2, tid);   // r2: len 1256 -> read as 1255
  __syncthreads();
  idwt_lds<true, false>(sa2, nullptr, NB2, sa1, tid);  // r1: len 2504 -> read as 2503
  __syncthreads();
  idwt_glob<true, false>(sa1, nullptr, NB1, out_physio + (size_t)b * NROW, tid);

  // identity = waverec([0, 0, 0, d2, d1]); first two idwt levels are zero
  idwt_lds<false, true>(nullptr, sd2, NB2, sx, tid);   // s1: len 2504 -> read as 2503
  __syncthreads();
  idwt_glob<true, true>(sx, sd1, NB1, out_identity + (size_t)b * NROW, tid);
}

extern "C" void kernel_launch(void* const* d_in, const int* in_sizes, int n_in,
                              void* d_out, int out_size, void* d_ws, size_t ws_size,
                              hipStream_t stream) {
  const float* x = (const float*)d_in[0];
  float* out = (float*)d_out;
  const int B = in_sizes[0] / NROW;  // 4096
  wavelet_kernel<<<dim3(B), dim3(NTHR), 0, stream>>>(x, out, out + (size_t)B * NROW);
}

// Round 3
// 62.964 us; speedup vs baseline: 1.6045x; 1.6045x over previous
//
#include <hip/hip_runtime.h>

#define NTHR 256
#define NROW 5000
#define NB1 2503
#define NB2 1255
#define NB3 631
#define NB4 319

// db4 filters (exact values from reference)
__device__ __constant__ float DEC_LO[8] = {
    -0.010597401784997278f, 0.032883011666982945f, 0.030841381835986965f,
    -0.18703481171888114f, -0.02798376941698385f, 0.6308807679295904f,
    0.7148465705525415f, 0.23037781330885523f};
__device__ __constant__ float DEC_HI[8] = {
    -0.23037781330885523f, 0.7148465705525415f, -0.6308807679295904f,
    -0.02798376941698385f, 0.18703481171888114f, 0.030841381835986965f,
    -0.032883011666982945f, -0.010597401784997278f};
__device__ __constant__ float REC_LO[8] = {
    0.23037781330885523f, 0.7148465705525415f, 0.6308807679295904f,
    -0.02798376941698385f, -0.18703481171888114f, 0.030841381835986965f,
    0.032883011666982945f, -0.010597401784997278f};
__device__ __constant__ float REC_HI[8] = {
    -0.010597401784997278f, -0.032883011666982945f, 0.030841381835986965f,
    0.18703481171888114f, -0.02798376941698385f, -0.6308807679295904f,
    0.7148465705525415f, -0.23037781330885523f};

__device__ __forceinline__ void dwt_accum(const float v[8], float& sa, float& sd) {
  sa = 0.f; sd = 0.f;
#pragma unroll
  for (int j = 0; j < 8; ++j) {
    sa = fmaf(DEC_LO[7 - j], v[j], sa);
    sd = fmaf(DEC_HI[7 - j], v[j], sd);
  }
}

// level-1 DWT reading x from GLOBAL (interior fast path, float2 loads)
__device__ __forceinline__ void dwt_glob(const float* __restrict__ x, int n, int n_out,
                                         float* __restrict__ oa, float* __restrict__ od,
                                         int tid) {
  for (int i = tid; i < n_out; i += NTHR) {
    float v[8];
    if (i >= 3 && 2 * i + 1 < n) {
      // taps cover x[2i-6 .. 2i+1], all interior; 2i-6 even -> 8B aligned
      const float2* s2 = reinterpret_cast<const float2*>(x + 2 * i - 6);
#pragma unroll
      for (int j = 0; j < 4; ++j) {
        const float2 p = s2[j];
        v[2 * j] = p.x;
        v[2 * j + 1] = p.y;
      }
    } else {
#pragma unroll
      for (int j = 0; j < 8; ++j) {
        const int p = 2 * i + j;
        const int q = (p < 6) ? (5 - p) : ((p < n + 6) ? (p - 6) : (2 * n + 5 - p));
        v[j] = x[q];
      }
    }
    float sa, sd;
    dwt_accum(v, sa, sd);
    oa[i] = sa;
    od[i] = sd;
  }
}

// DWT from LDS (interior fast path)
__device__ __forceinline__ void dwt_step(const float* __restrict__ src, int n, int n_out,
                                         float* __restrict__ oa, float* __restrict__ od,
                                         int tid) {
  for (int i = tid; i < n_out; i += NTHR) {
    float v[8];
    if (i >= 3 && 2 * i + 1 < n) {
      const float* s = src + 2 * i - 6;
#pragma unroll
      for (int j = 0; j < 8; ++j) v[j] = s[j];
    } else {
#pragma unroll
      for (int j = 0; j < 8; ++j) {
        const int p = 2 * i + j;
        const int q = (p < 6) ? (5 - p) : ((p < n + 6) ? (p - 6) : (2 * n + 5 - p));
        v[j] = src[q];
      }
    }
    float sa, sd;
    dwt_accum(v, sa, sd);
    oa[i] = sa;
    od[i] = sd;
  }
}

// out[2i], out[2i+1] from ca[i..i+3], cd[i..i+3]; i in [0, n-4]; out len 2n-6
template <bool CA, bool CD>
__device__ __forceinline__ void idwt_lds(const float* __restrict__ ca,
                                         const float* __restrict__ cd, int n,
                                         float* __restrict__ out, int tid) {
  for (int i = tid; i <= n - 4; i += NTHR) {
    float e = 0.f, o = 0.f;
#pragma unroll
    for (int s = 0; s < 4; ++s) {
      const int j = i + 3 - s;
      if (CA) {
        const float a = ca[j];
        e = fmaf(REC_LO[2 * s], a, e);
        o = fmaf(REC_LO[2 * s + 1], a, o);
      }
      if (CD) {
        const float d = cd[j];
        e = fmaf(REC_HI[2 * s], d, e);
        o = fmaf(REC_HI[2 * s + 1], d, o);
      }
    }
    out[2 * i] = e;
    out[2 * i + 1] = o;
  }
}

template <bool CA, bool CD>
__device__ __forceinline__ void idwt_glob(const float* __restrict__ ca,
                                          const float* __restrict__ cd, int n,
                                          float* __restrict__ out, int tid) {
  float2* out2 = reinterpret_cast<float2*>(out);
  for (int i = tid; i <= n - 4; i += NTHR) {
    float e = 0.f, o = 0.f;
#pragma unroll
    for (int s = 0; s < 4; ++s) {
      const int j = i + 3 - s;
      if (CA) {
        const float a = ca[j];
        e = fmaf(REC_LO[2 * s], a, e);
        o = fmaf(REC_LO[2 * s + 1], a, o);
      }
      if (CD) {
        const float d = cd[j];
        e = fmaf(REC_HI[2 * s], d, e);
        o = fmaf(REC_HI[2 * s + 1], d, o);
      }
    }
    out2[i] = make_float2(e, o);
  }
}

__global__ __launch_bounds__(NTHR) void wavelet_kernel(const float* __restrict__ x,
                                                       float* __restrict__ out_physio,
                                                       float* __restrict__ out_identity) {
  // 9424 floats = 37.7 KB -> 4 blocks/CU (was 57.8 KB -> 2 blocks/CU)
  __shared__ __align__(16) float sa1[2504];  // a1; later r1 (physio); later s1 (identity)
  __shared__ float sd1[2504];
  __shared__ float sa2[1256];                // a2; later r2
  __shared__ float sd2[1256];
  __shared__ float sa3[632];                 // a3; later r3
  __shared__ float sd3[632];
  __shared__ float sa4[320];
  __shared__ float sd4[320];

  const int b = blockIdx.x;
  const int tid = threadIdx.x;
  const float* xrow = x + (size_t)b * NROW;

  // decomposition (level 1 straight from global; x is L1/L2-resident per block)
  dwt_glob(xrow, NROW, NB1, sa1, sd1, tid);
  __syncthreads();
  dwt_step(sa1, NB1, NB2, sa2, sd2, tid);
  __syncthreads();
  dwt_step(sa2, NB2, NB3, sa3, sd3, tid);
  __syncthreads();
  dwt_step(sa3, NB3, NB4, sa4, sd4, tid);
  __syncthreads();

  // physio = waverec([a4, d4, d3, 0, 0])
  idwt_lds<true, true>(sa4, sd4, NB4, sa3, tid);   // r3: len 632 -> read as 631
  __syncthreads();
  idwt_lds<true, true>(sa3, sd3, NB3, sa2, tid);   // r2: len 1256 -> read as 1255
  __syncthreads();
  idwt_lds<true, false>(sa2, nullptr, NB2, sa1, tid);  // r1: len 2504 -> read as 2503
  __syncthreads();
  idwt_glob<true, false>(sa1, nullptr, NB1, out_physio + (size_t)b * NROW, tid);
  __syncthreads();  // sa1 about to be overwritten with s1

  // identity = waverec([0, 0, 0, d2, d1]); first two idwt levels are zero
  idwt_lds<false, true>(nullptr, sd2, NB2, sa1, tid);  // s1: len 2504 -> read as 2503
  __syncthreads();
  idwt_glob<true, true>(sa1, sd1, NB1, out_identity + (size_t)b * NROW, tid);
}

extern "C" void kernel_launch(void* const* d_in, const int* in_sizes, int n_in,
                              void* d_out, int out_size, void* d_ws, size_t ws_size,
                              hipStream_t stream) {
  const float* x = (const float*)d_in[0];
  float* out = (float*)d_out;
  const int B = in_sizes[0] / NROW;  // 4096
  wavelet_kernel<<<dim3(B), dim3(NTHR), 0, stream>>>(x, out, out + (size_t)B * NROW);
}

// Round 4
// 53.592 us; speedup vs baseline: 1.8850x; 1.1749x over previous
//
#include <hip/hip_runtime.h>

#define NTHR 256
#define NROW 5000
#define NB1 2503
#define NB2 1255
#define NB3 631
#define NB4 319

// db4 filters (exact values from reference)
__device__ __constant__ float DEC_LO[8] = {
    -0.010597401784997278f, 0.032883011666982945f, 0.030841381835986965f,
    -0.18703481171888114f, -0.02798376941698385f, 0.6308807679295904f,
    0.7148465705525415f, 0.23037781330885523f};
__device__ __constant__ float DEC_HI[8] = {
    -0.23037781330885523f, 0.7148465705525415f, -0.6308807679295904f,
    -0.02798376941698385f, 0.18703481171888114f, 0.030841381835986965f,
    -0.032883011666982945f, -0.010597401784997278f};
__device__ __constant__ float REC_LO[8] = {
    0.23037781330885523f, 0.7148465705525415f, 0.6308807679295904f,
    -0.02798376941698385f, -0.18703481171888114f, 0.030841381835986965f,
    0.032883011666982945f, -0.010597401784997278f};
__device__ __constant__ float REC_HI[8] = {
    -0.010597401784997278f, -0.032883011666982945f, 0.030841381835986965f,
    0.18703481171888114f, -0.02798376941698385f, -0.6308807679295904f,
    0.7148465705525415f, -0.23037781330885523f};

// two adjacent dwt outputs (i0, i0+1) from v[0..9] (taps p = 2*i0 + j)
__device__ __forceinline__ void dwt_accum2(const float v[10], float& sa0, float& sd0,
                                           float& sa1, float& sd1) {
  sa0 = sd0 = sa1 = sd1 = 0.f;
#pragma unroll
  for (int j = 0; j < 8; ++j) {
    const float lo = DEC_LO[7 - j], hi = DEC_HI[7 - j];
    sa0 = fmaf(lo, v[j], sa0);
    sd0 = fmaf(hi, v[j], sd0);
    sa1 = fmaf(lo, v[j + 2], sa1);
    sd1 = fmaf(hi, v[j + 2], sd1);
  }
}

// level-1 DWT reading x from GLOBAL, 2 outputs/thread
__device__ __forceinline__ void dwt_glob(const float* __restrict__ x, int n, int n_out,
                                         float* __restrict__ oa, float* __restrict__ od,
                                         int tid) {
  const int npair = (n_out + 1) / 2;
  for (int t = tid; t < npair; t += NTHR) {
    const int i0 = 2 * t;
    float v[10];
    if (i0 >= 3 && 2 * i0 + 4 <= n) {
      // taps x[2i0-6 .. 2i0+3], interior; 2i0-6 even -> 8B aligned
      const float2* s2 = reinterpret_cast<const float2*>(x + 2 * i0 - 6);
#pragma unroll
      for (int j = 0; j < 5; ++j) {
        const float2 p = s2[j];
        v[2 * j] = p.x;
        v[2 * j + 1] = p.y;
      }
    } else {
#pragma unroll
      for (int j = 0; j < 10; ++j) {
        const int p = 2 * i0 + j;
        const int q = (p < 6) ? (5 - p) : ((p < n + 6) ? (p - 6) : (2 * n + 5 - p));
        v[j] = x[q];
      }
    }
    float sa0, sd0, sa1, sd1;
    dwt_accum2(v, sa0, sd0, sa1, sd1);
    if (i0 + 1 < n_out) {
      *reinterpret_cast<float2*>(oa + i0) = make_float2(sa0, sa1);
      *reinterpret_cast<float2*>(od + i0) = make_float2(sd0, sd1);
    } else {
      oa[i0] = sa0;
      od[i0] = sd0;
    }
  }
}

// DWT from LDS, 2 outputs/thread
__device__ __forceinline__ void dwt_step(const float* __restrict__ src, int n, int n_out,
                                         float* __restrict__ oa, float* __restrict__ od,
                                         int tid) {
  const int npair = (n_out + 1) / 2;
  for (int t = tid; t < npair; t += NTHR) {
    const int i0 = 2 * t;
    float v[10];
    if (i0 >= 3 && 2 * i0 + 4 <= n) {
      const float2* s2 = reinterpret_cast<const float2*>(src + 2 * i0 - 6);
#pragma unroll
      for (int j = 0; j < 5; ++j) {
        const float2 p = s2[j];
        v[2 * j] = p.x;
        v[2 * j + 1] = p.y;
      }
    } else {
#pragma unroll
      for (int j = 0; j < 10; ++j) {
        const int p = 2 * i0 + j;
        const int q = (p < 6) ? (5 - p) : ((p < n + 6) ? (p - 6) : (2 * n + 5 - p));
        v[j] = src[q];
      }
    }
    float sa0, sd0, sa1, sd1;
    dwt_accum2(v, sa0, sd0, sa1, sd1);
    if (i0 + 1 < n_out) {
      *reinterpret_cast<float2*>(oa + i0) = make_float2(sa0, sa1);
      *reinterpret_cast<float2*>(od + i0) = make_float2(sd0, sd1);
    } else {
      oa[i0] = sa0;
      od[i0] = sd0;
    }
  }
}

// idwt pair: loads c[i0..i0+4], produces out[2i0..2i0+3] as float4.
// i count (n-3) is even for every stage here -> no tails.
template <bool CA, bool CD>
__device__ __forceinline__ void idwt_pair(const float* __restrict__ ca,
                                          const float* __restrict__ cd, int i0,
                                          float4& r) {
  float a[5], d[5];
  if (CA) {
    const float2 u0 = *reinterpret_cast<const float2*>(ca + i0);
    const float2 u1 = *reinterpret_cast<const float2*>(ca + i0 + 2);
    a[0] = u0.x; a[1] = u0.y; a[2] = u1.x; a[3] = u1.y; a[4] = ca[i0 + 4];
  }
  if (CD) {
    const float2 w0 = *reinterpret_cast<const float2*>(cd + i0);
    const float2 w1 = *reinterpret_cast<const float2*>(cd + i0 + 2);
    d[0] = w0.x; d[1] = w0.y; d[2] = w1.x; d[3] = w1.y; d[4] = cd[i0 + 4];
  }
  float e0 = 0.f, o0 = 0.f, e1 = 0.f, o1 = 0.f;
#pragma unroll
  for (int s = 0; s < 4; ++s) {
    const float rl0 = REC_LO[2 * s], rl1 = REC_LO[2 * s + 1];
    const float rh0 = REC_HI[2 * s], rh1 = REC_HI[2 * s + 1];
    if (CA) {
      e0 = fmaf(rl0, a[3 - s], e0);
      o0 = fmaf(rl1, a[3 - s], o0);
      e1 = fmaf(rl0, a[4 - s], e1);
      o1 = fmaf(rl1, a[4 - s], o1);
    }
    if (CD) {
      e0 = fmaf(rh0, d[3 - s], e0);
      o0 = fmaf(rh1, d[3 - s], o0);
      e1 = fmaf(rh0, d[4 - s], e1);
      o1 = fmaf(rh1, d[4 - s], o1);
    }
  }
  r = make_float4(e0, o0, e1, o1);
}

template <bool CA, bool CD>
__device__ __forceinline__ void idwt_lds(const float* __restrict__ ca,
                                         const float* __restrict__ cd, int n,
                                         float* __restrict__ out, int tid) {
  const int npair = (n - 3) / 2;
  float4* out4 = reinterpret_cast<float4*>(out);
  for (int t = tid; t < npair; t += NTHR) {
    float4 r;
    idwt_pair<CA, CD>(ca, cd, 2 * t, r);
    out4[t] = r;
  }
}

template <bool CA, bool CD>
__device__ __forceinline__ void idwt_glob(const float* __restrict__ ca,
                                          const float* __restrict__ cd, int n,
                                          float* __restrict__ out, int tid) {
  const int npair = (n - 3) / 2;
  float4* out4 = reinterpret_cast<float4*>(out);
  for (int t = tid; t < npair; t += NTHR) {
    float4 r;
    idwt_pair<CA, CD>(ca, cd, 2 * t, r);
    out4[t] = r;
  }
}

__global__ __launch_bounds__(NTHR) void wavelet_kernel(const float* __restrict__ x,
                                                       float* __restrict__ out_physio,
                                                       float* __restrict__ out_identity) {
  // 9424 floats = 37.7 KB -> 4 blocks/CU
  __shared__ __align__(16) float sa1[2504];  // a1; later r1 (physio); later s1 (identity)
  __shared__ __align__(16) float sd1[2504];
  __shared__ __align__(16) float sa2[1256];  // a2; later r2
  __shared__ __align__(16) float sd2[1256];
  __shared__ __align__(16) float sa3[632];   // a3; later r3
  __shared__ __align__(16) float sd3[632];
  __shared__ __align__(16) float sa4[320];
  __shared__ __align__(16) float sd4[320];

  const int b = blockIdx.x;
  const int tid = threadIdx.x;
  const float* xrow = x + (size_t)b * NROW;

  // decomposition (level 1 straight from global; x row is L1/L2-resident)
  dwt_glob(xrow, NROW, NB1, sa1, sd1, tid);
  __syncthreads();
  dwt_step(sa1, NB1, NB2, sa2, sd2, tid);
  __syncthreads();
  dwt_step(sa2, NB2, NB3, sa3, sd3, tid);
  __syncthreads();
  dwt_step(sa3, NB3, NB4, sa4, sd4, tid);
  __syncthreads();

  // physio = waverec([a4, d4, d3, 0, 0])
  idwt_lds<true, true>(sa4, sd4, NB4, sa3, tid);   // r3: 632 floats -> read as 631
  __syncthreads();
  idwt_lds<true, true>(sa3, sd3, NB3, sa2, tid);   // r2: 1256 -> read as 1255
  __syncthreads();
  idwt_lds<true, false>(sa2, nullptr, NB2, sa1, tid);  // r1: 2504 -> read as 2503
  __syncthreads();
  idwt_glob<true, false>(sa1, nullptr, NB1, out_physio + (size_t)b * NROW, tid);
  __syncthreads();  // sa1 about to be overwritten with s1

  // identity = waverec([0, 0, 0, d2, d1]); first two idwt levels are zero
  idwt_lds<false, true>(nullptr, sd2, NB2, sa1, tid);  // s1: 2504 -> read as 2503
  __syncthreads();
  idwt_glob<true, true>(sa1, sd1, NB1, out_identity + (size_t)b * NROW, tid);
}

extern "C" void kernel_launch(void* const* d_in, const int* in_sizes, int n_in,
                              void* d_out, int out_size, void* d_ws, size_t ws_size,
                              hipStream_t stream) {
  const float* x = (const float*)d_in[0];
  float* out = (float*)d_out;
  const int B = in_sizes[0] / NROW;  // 4096
  wavelet_kernel<<<dim3(B), dim3(NTHR), 0, stream>>>(x, out, out + (size_t)B * NROW);
}

// Round 5
// 47.738 us; speedup vs baseline: 2.1162x; 1.1226x over previous
//
#include <hip/hip_runtime.h>

#define NTHR 512
#define NROW 5000
#define NB1 2503
#define NB2 1255
#define NB3 631
#define NB4 319

// db4 filters (exact values from reference)
__device__ __constant__ float DEC_LO[8] = {
    -0.010597401784997278f, 0.032883011666982945f, 0.030841381835986965f,
    -0.18703481171888114f, -0.02798376941698385f, 0.6308807679295904f,
    0.7148465705525415f, 0.23037781330885523f};
__device__ __constant__ float DEC_HI[8] = {
    -0.23037781330885523f, 0.7148465705525415f, -0.6308807679295904f,
    -0.02798376941698385f, 0.18703481171888114f, 0.030841381835986965f,
    -0.032883011666982945f, -0.010597401784997278f};
__device__ __constant__ float REC_LO[8] = {
    0.23037781330885523f, 0.7148465705525415f, 0.6308807679295904f,
    -0.02798376941698385f, -0.18703481171888114f, 0.030841381835986965f,
    0.032883011666982945f, -0.010597401784997278f};
__device__ __constant__ float REC_HI[8] = {
    -0.010597401784997278f, -0.032883011666982945f, 0.030841381835986965f,
    0.18703481171888114f, -0.02798376941698385f, -0.6308807679295904f,
    0.7148465705525415f, -0.23037781330885523f};

// two adjacent dwt outputs (i0, i0+1) from v[0..9] (taps p = 2*i0 + j)
__device__ __forceinline__ void dwt_accum2(const float v[10], float& sa0, float& sd0,
                                           float& sa1, float& sd1) {
  sa0 = sd0 = sa1 = sd1 = 0.f;
#pragma unroll
  for (int j = 0; j < 8; ++j) {
    const float lo = DEC_LO[7 - j], hi = DEC_HI[7 - j];
    sa0 = fmaf(lo, v[j], sa0);
    sd0 = fmaf(hi, v[j], sd0);
    sa1 = fmaf(lo, v[j + 2], sa1);
    sd1 = fmaf(hi, v[j + 2], sd1);
  }
}

// level-1 DWT reading x from GLOBAL, 2 outputs/thread
__device__ __forceinline__ void dwt_glob(const float* __restrict__ x, int n, int n_out,
                                         float* __restrict__ oa, float* __restrict__ od,
                                         int tid) {
  const int npair = (n_out + 1) / 2;
  for (int t = tid; t < npair; t += NTHR) {
    const int i0 = 2 * t;
    float v[10];
    if (i0 >= 3 && 2 * i0 + 4 <= n) {
      // taps x[2i0-6 .. 2i0+3], interior; 2i0-6 even -> 8B aligned
      const float2* s2 = reinterpret_cast<const float2*>(x + 2 * i0 - 6);
#pragma unroll
      for (int j = 0; j < 5; ++j) {
        const float2 p = s2[j];
        v[2 * j] = p.x;
        v[2 * j + 1] = p.y;
      }
    } else {
#pragma unroll
      for (int j = 0; j < 10; ++j) {
        const int p = 2 * i0 + j;
        const int q = (p < 6) ? (5 - p) : ((p < n + 6) ? (p - 6) : (2 * n + 5 - p));
        v[j] = x[q];
      }
    }
    float sa0, sd0, sa1, sd1;
    dwt_accum2(v, sa0, sd0, sa1, sd1);
    if (i0 + 1 < n_out) {
      *reinterpret_cast<float2*>(oa + i0) = make_float2(sa0, sa1);
      *reinterpret_cast<float2*>(od + i0) = make_float2(sd0, sd1);
    } else {
      oa[i0] = sa0;
      od[i0] = sd0;
    }
  }
}

// DWT from LDS, 2 outputs/thread
__device__ __forceinline__ void dwt_step(const float* __restrict__ src, int n, int n_out,
                                         float* __restrict__ oa, float* __restrict__ od,
                                         int tid) {
  const int npair = (n_out + 1) / 2;
  for (int t = tid; t < npair; t += NTHR) {
    const int i0 = 2 * t;
    float v[10];
    if (i0 >= 3 && 2 * i0 + 4 <= n) {
      const float2* s2 = reinterpret_cast<const float2*>(src + 2 * i0 - 6);
#pragma unroll
      for (int j = 0; j < 5; ++j) {
        const float2 p = s2[j];
        v[2 * j] = p.x;
        v[2 * j + 1] = p.y;
      }
    } else {
#pragma unroll
      for (int j = 0; j < 10; ++j) {
        const int p = 2 * i0 + j;
        const int q = (p < 6) ? (5 - p) : ((p < n + 6) ? (p - 6) : (2 * n + 5 - p));
        v[j] = src[q];
      }
    }
    float sa0, sd0, sa1, sd1;
    dwt_accum2(v, sa0, sd0, sa1, sd1);
    if (i0 + 1 < n_out) {
      *reinterpret_cast<float2*>(oa + i0) = make_float2(sa0, sa1);
      *reinterpret_cast<float2*>(od + i0) = make_float2(sd0, sd1);
    } else {
      oa[i0] = sa0;
      od[i0] = sd0;
    }
  }
}

// idwt pair: loads c[i0..i0+4], produces out[2i0..2i0+3] as float4.
// i count (n-3) is even for every stage here -> no tails.
template <bool CA, bool CD>
__device__ __forceinline__ void idwt_pair(const float* __restrict__ ca,
                                          const float* __restrict__ cd, int i0,
                                          float4& r) {
  float a[5], d[5];
  if (CA) {
    const float2 u0 = *reinterpret_cast<const float2*>(ca + i0);
    const float2 u1 = *reinterpret_cast<const float2*>(ca + i0 + 2);
    a[0] = u0.x; a[1] = u0.y; a[2] = u1.x; a[3] = u1.y; a[4] = ca[i0 + 4];
  }
  if (CD) {
    const float2 w0 = *reinterpret_cast<const float2*>(cd + i0);
    const float2 w1 = *reinterpret_cast<const float2*>(cd + i0 + 2);
    d[0] = w0.x; d[1] = w0.y; d[2] = w1.x; d[3] = w1.y; d[4] = cd[i0 + 4];
  }
  float e0 = 0.f, o0 = 0.f, e1 = 0.f, o1 = 0.f;
#pragma unroll
  for (int s = 0; s < 4; ++s) {
    const float rl0 = REC_LO[2 * s], rl1 = REC_LO[2 * s + 1];
    const float rh0 = REC_HI[2 * s], rh1 = REC_HI[2 * s + 1];
    if (CA) {
      e0 = fmaf(rl0, a[3 - s], e0);
      o0 = fmaf(rl1, a[3 - s], o0);
      e1 = fmaf(rl0, a[4 - s], e1);
      o1 = fmaf(rl1, a[4 - s], o1);
    }
    if (CD) {
      e0 = fmaf(rh0, d[3 - s], e0);
      o0 = fmaf(rh1, d[3 - s], o0);
      e1 = fmaf(rh0, d[4 - s], e1);
      o1 = fmaf(rh1, d[4 - s], o1);
    }
  }
  r = make_float4(e0, o0, e1, o1);
}

template <bool CA, bool CD>
__device__ __forceinline__ void idwt_any(const float* __restrict__ ca,
                                         const float* __restrict__ cd, int n,
                                         float* __restrict__ out, int tid) {
  const int npair = (n - 3) / 2;
  float4* out4 = reinterpret_cast<float4*>(out);
  for (int t = tid; t < npair; t += NTHR) {
    float4 r;
    idwt_pair<CA, CD>(ca, cd, 2 * t, r);
    out4[t] = r;
  }
}

__global__ __launch_bounds__(NTHR, 8) void wavelet_kernel(
    const float* __restrict__ x, float* __restrict__ out_physio,
    float* __restrict__ out_identity) {
  // Aliased LDS plan: 7520 floats = 30,080 B -> 4 blocks/CU at 512 thr (wave cap)
  // A: a1 -> {a3@0, d3@+632, a4@+1264, d4@+1584} -> r3@0 -> r1 -> s1
  // B: d1 (live to the end)
  // C: a2 -> r2
  // D: d2 (live until s1)
  __shared__ __align__(16) float A[2504];
  __shared__ __align__(16) float B[2504];
  __shared__ __align__(16) float C[1256];
  __shared__ __align__(16) float D[1256];

  float* const a3 = A;            // 631 floats @ A[0..630]
  float* const d3 = A + 632;      // 631 floats @ A[632..1262]
  float* const a4 = A + 1264;     // 319 floats
  float* const d4 = A + 1584;     // 319 floats (ends at 1902 < 2504)

  const int b = blockIdx.x;
  const int tid = threadIdx.x;
  const float* xrow = x + (size_t)b * NROW;

  // decomposition (level 1 straight from global; x row is L1/L2-resident)
  dwt_glob(xrow, NROW, NB1, A, B, tid);        // a1 -> A, d1 -> B
  __syncthreads();
  dwt_step(A, NB1, NB2, C, D, tid);            // a2 -> C, d2 -> D (reads A)
  __syncthreads();
  dwt_step(C, NB2, NB3, a3, d3, tid);          // a1 dead: a3/d3 into A
  __syncthreads();
  dwt_step(a3, NB3, NB4, a4, d4, tid);         // reads A[0..630], writes A[1264..] (disjoint)
  __syncthreads();

  // physio = waverec([a4, d4, d3, 0, 0])
  idwt_any<true, true>(a4, d4, NB4, A, tid);   // r3 -> A[0..631] (a3 dead; reads A[1264..])
  __syncthreads();
  idwt_any<true, true>(A, d3, NB3, C, tid);    // r2 -> C (a2 dead; reads A[0..630],A[632..])
  __syncthreads();
  idwt_any<true, false>(C, nullptr, NB2, A, tid);  // r1 -> A[0..2503] (r3/d3/a4/d4 dead)
  __syncthreads();
  idwt_any<true, false>(A, nullptr, NB1, out_physio + (size_t)b * NROW, tid);
  __syncthreads();  // A about to be overwritten with s1

  // identity = waverec([0, 0, 0, d2, d1])
  idwt_any<false, true>(nullptr, D, NB2, A, tid);  // s1 -> A[0..2503]
  __syncthreads();
  idwt_any<true, true>(A, B, NB1, out_identity + (size_t)b * NROW, tid);
}

extern "C" void kernel_launch(void* const* d_in, const int* in_sizes, int n_in,
                              void* d_out, int out_size, void* d_ws, size_t ws_size,
                              hipStream_t stream) {
  const float* x = (const float*)d_in[0];
  float* out = (float*)d_out;
  const int B = in_sizes[0] / NROW;  // 4096
  wavelet_kernel<<<dim3(B), dim3(NTHR), 0, stream>>>(x, out, out + (size_t)B * NROW);
}